// Round 1
// baseline (938.461 us; speedup 1.0000x reference)
//
#include <hip/hip_runtime.h>
#include <hip/hip_bf16.h>

#define B_    1024
#define L_    100
#define D_    512
#define F_    12
#define K1    6144   // 12*512
#define N1    512
#define N2    256
#define N3    128
#define SPLITK 4
#define KSEG  (K1/SPLITK)   // 1536

typedef short  bf16x8 __attribute__((ext_vector_type(8)));
typedef float  f32x4  __attribute__((ext_vector_type(4)));

static __device__ __forceinline__ unsigned short f2bf(float x) {
  __hip_bfloat16 h = __float2bfloat16(x);
  return *reinterpret_cast<unsigned short*>(&h);
}

struct PoolArgs {
  const float* tbl[12];
  const int*   idx[12];   // f<3: id arrays [B]; f>=3: seq arrays [B*L]
};

// ---------------------------------------------------------------------------
// Kernel 1: embedding gather + mean-pool -> X bf16 [B, 12*D]
// grid (B, 12), block 128. Each thread owns 4 consecutive columns (float4).
// ---------------------------------------------------------------------------
__global__ __launch_bounds__(128) void pool_kernel(PoolArgs args,
                                                   unsigned short* __restrict__ X) {
  const int b = blockIdx.x;
  const int f = blockIdx.y;
  const int d = threadIdx.x * 4;
  const float* __restrict__ T = args.tbl[f];
  float a0 = 0.f, a1 = 0.f, a2 = 0.f, a3 = 0.f;
  if (f < 3) {
    const int row = args.idx[f][b];
    const float4 v = *(const float4*)(T + (size_t)row * D_ + d);
    a0 = v.x; a1 = v.y; a2 = v.z; a3 = v.w;
  } else {
    const int* __restrict__ seq = args.idx[f] + b * L_;
    #pragma unroll 4
    for (int l = 0; l < L_; ++l) {
      const float4 v = *(const float4*)(T + (size_t)seq[l] * D_ + d);
      a0 += v.x; a1 += v.y; a2 += v.z; a3 += v.w;
    }
    a0 *= 0.01f; a1 *= 0.01f; a2 *= 0.01f; a3 *= 0.01f;
  }
  ushort4 u;
  u.x = f2bf(a0); u.y = f2bf(a1); u.z = f2bf(a2); u.w = f2bf(a3);
  *(ushort4*)(X + (size_t)b * K1 + f * D_ + d) = u;
}

// ---------------------------------------------------------------------------
// Kernel 2: W1 [K1, N1] f32 row-major  ->  W1t [N1, K1] bf16 (transposed)
// so GEMM B-fragments (B[k][n], k contiguous per lane) are 16B vector loads.
// ---------------------------------------------------------------------------
__global__ __launch_bounds__(256) void w1t_kernel(const float* __restrict__ W1,
                                                  unsigned short* __restrict__ W1t) {
  __shared__ float tile[32][33];
  const int k0 = blockIdx.x * 32;
  const int n0 = blockIdx.y * 32;
  const int tx = threadIdx.x & 31;
  const int ty = threadIdx.x >> 5;   // 0..7
  #pragma unroll
  for (int i = 0; i < 4; ++i)
    tile[ty + 8 * i][tx] = W1[(size_t)(k0 + ty + 8 * i) * N1 + n0 + tx];
  __syncthreads();
  #pragma unroll
  for (int i = 0; i < 4; ++i)
    W1t[(size_t)(n0 + ty + 8 * i) * K1 + k0 + tx] = f2bf(tile[tx][ty + 8 * i]);
}

// ---------------------------------------------------------------------------
// Kernel 3: GEMM1  H1p[s] = X[:, sK:(s+1)K] @ W1[sK:(s+1)K, :]   (bf16 MFMA)
// LDS-free: both A and B fragments are direct 16B global loads (W1t rows are
// L2/LLC resident, X is LLC resident). Wave tile 32x32 = 2x2 of 16x16x32.
// grid (128, SPLITK) x 256 thr: g = bx*4+wave in [0,512) -> 32 m-tiles x 16 n-tiles.
// ---------------------------------------------------------------------------
__global__ __launch_bounds__(256) void gemm1_kernel(const unsigned short* __restrict__ X,
                                                    const unsigned short* __restrict__ W1t,
                                                    float* __restrict__ H1p) {
  const int w    = threadIdx.x >> 6;
  const int lane = threadIdx.x & 63;
  const int g      = blockIdx.x * 4 + w;       // 0..511
  const int tile_m = g >> 4;                   // 0..31
  const int tile_n = g & 15;                   // 0..15
  const int s  = blockIdx.y;                   // split-K index
  const int m0 = tile_m * 32;
  const int n0 = tile_n * 32;
  const int quad = lane >> 4;
  const int r16  = lane & 15;

  const short* __restrict__ Xs = (const short*)X;
  const short* __restrict__ Ws = (const short*)W1t;
  const int k0 = s * KSEG;
  const short* ax0 = Xs + (size_t)(m0 + r16) * K1 + k0 + quad * 8;
  const short* ax1 = ax0 + (size_t)16 * K1;
  const short* bx0 = Ws + (size_t)(n0 + r16) * K1 + k0 + quad * 8;
  const short* bx1 = bx0 + (size_t)16 * K1;

  f32x4 acc00 = {0.f, 0.f, 0.f, 0.f}, acc01 = acc00, acc10 = acc00, acc11 = acc00;

  #pragma unroll 4
  for (int kk = 0; kk < KSEG; kk += 32) {
    bf16x8 a0 = *(const bf16x8*)(ax0 + kk);
    bf16x8 a1 = *(const bf16x8*)(ax1 + kk);
    bf16x8 b0 = *(const bf16x8*)(bx0 + kk);
    bf16x8 b1 = *(const bf16x8*)(bx1 + kk);
    acc00 = __builtin_amdgcn_mfma_f32_16x16x32_bf16(a0, b0, acc00, 0, 0, 0);
    acc01 = __builtin_amdgcn_mfma_f32_16x16x32_bf16(a0, b1, acc01, 0, 0, 0);
    acc10 = __builtin_amdgcn_mfma_f32_16x16x32_bf16(a1, b0, acc10, 0, 0, 0);
    acc11 = __builtin_amdgcn_mfma_f32_16x16x32_bf16(a1, b1, acc11, 0, 0, 0);
  }

  // C/D layout (m89-verified): col = lane&15, row = quad*4 + reg
  float* outp = H1p + (size_t)s * (B_ * N1);
  #pragma unroll
  for (int rr = 0; rr < 4; ++rr) {
    const int row0 = m0 + quad * 4 + rr;
    const int col0 = n0 + r16;
    outp[(size_t)row0 * N1 + col0]               = acc00[rr];
    outp[(size_t)row0 * N1 + col0 + 16]          = acc01[rr];
    outp[(size_t)(row0 + 16) * N1 + col0]        = acc10[rr];
    outp[(size_t)(row0 + 16) * N1 + col0 + 16]   = acc11[rr];
  }
}

// ---------------------------------------------------------------------------
// Kernel 4: combine split-K partials + b1 + relu, then layer2 (relu) and
// layer3 (linear). One block per batch row, 256 threads, LDS intermediates.
// ---------------------------------------------------------------------------
__global__ __launch_bounds__(256) void mlp23_kernel(const float* __restrict__ H1p,
                                                    const float* __restrict__ b1,
                                                    const float* __restrict__ W2,
                                                    const float* __restrict__ b2,
                                                    const float* __restrict__ W3,
                                                    const float* __restrict__ b3,
                                                    float* __restrict__ out) {
  __shared__ float h1s[N1];
  __shared__ float h2s[N2];
  const int b = blockIdx.x;
  const int t = threadIdx.x;

  #pragma unroll
  for (int j = t; j < N1; j += 256) {
    float v = b1[j];
    v += H1p[0 * (B_ * N1) + (size_t)b * N1 + j];
    v += H1p[1 * (B_ * N1) + (size_t)b * N1 + j];
    v += H1p[2 * (B_ * N1) + (size_t)b * N1 + j];
    v += H1p[3 * (B_ * N1) + (size_t)b * N1 + j];
    h1s[j] = fmaxf(v, 0.f);
  }
  __syncthreads();

  // layer 2: thread t -> output column t (N2 = 256)
  float v2 = b2[t];
  #pragma unroll 8
  for (int k = 0; k < N1; ++k)
    v2 = fmaf(h1s[k], W2[(size_t)k * N2 + t], v2);
  h2s[t] = fmaxf(v2, 0.f);
  __syncthreads();

  // layer 3: threads 0..127 -> output column t (N3 = 128)
  if (t < N3) {
    float v3 = b3[t];
    #pragma unroll 8
    for (int k = 0; k < N2; ++k)
      v3 = fmaf(h2s[k], W3[(size_t)k * N3 + t], v3);
    out[(size_t)b * N3 + t] = v3;
  }
}

// ---------------------------------------------------------------------------
extern "C" void kernel_launch(void* const* d_in, const int* in_sizes, int n_in,
                              void* d_out, int out_size, void* d_ws, size_t ws_size,
                              hipStream_t stream) {
  char* ws = (char*)d_ws;
  unsigned short* X   = (unsigned short*)ws;                         // 1024*6144*2  = 12,582,912 B
  unsigned short* W1t = (unsigned short*)(ws + 12582912);            // 512*6144*2   =  6,291,456 B
  float*          H1p = (float*)(ws + 12582912 + 6291456);           // 4*1024*512*4 =  8,388,608 B

  PoolArgs pa;
  for (int i = 0; i < 12; ++i) pa.tbl[i] = (const float*)d_in[i];
  pa.idx[0] = (const int*)d_in[18];   // id_name
  pa.idx[1] = (const int*)d_in[19];   // id_collab
  pa.idx[2] = (const int*)d_in[20];   // id_track_can
  for (int i = 3; i < 12; ++i) pa.idx[i] = (const int*)d_in[18 + i]; // seq_* (21..29)

  pool_kernel<<<dim3(B_, F_), 128, 0, stream>>>(pa, X);
  w1t_kernel<<<dim3(K1 / 32, N1 / 32), 256, 0, stream>>>((const float*)d_in[12], W1t);
  gemm1_kernel<<<dim3(128, SPLITK), 256, 0, stream>>>(X, W1t, H1p);
  mlp23_kernel<<<dim3(B_), 256, 0, stream>>>(H1p, (const float*)d_in[13],
                                             (const float*)d_in[14], (const float*)d_in[15],
                                             (const float*)d_in[16], (const float*)d_in[17],
                                             (float*)d_out);
}